// Round 4
// baseline (77.396 us; speedup 1.0000x reference)
//
#include <hip/hip_runtime.h>
#include <cmath>

// Local contrast normalization, streaming row-pipeline version.
// x: [64,512,512,1] f32; 9x9 Gaussian (separable, asymmetric center 4.5),
// SAME zero padding; out = keep ? d/sqrt(conv(d^2)) : d, keep = norm > 0.5.
//
// Block = 128 threads (2 waves) = one full 512-px row, 1 float4 per lane.
// Each block streams a 32-row output strip top-to-bottom with an 8-row
// pipeline: step s loads x(r), r = R0-8+s; computes hx(r) into a 12-deep
// register ring; mean/d at row r-4 (d -> 6-slot LDS ring, padded columns);
// h-conv(d^2) at r-4 into 12-deep h2 ring; output row r-8.
// All ring indices static via #pragma unroll 12 (48 = 4*12, 12%6==0).

struct W9 { float w[9]; };

#define HW     512
#define NF4    128      // float4 per image row
#define SROWS  32       // output rows per block
#define NSTEP  48       // SROWS + 16 (vertical dependency is +-8 rows)
#define DRING  6        // LDS d-ring depth (write@s, neighbor-read@s, out-read@s+4)
#define DPITCH 132      // f4 stride per ring slot: [pad][128 cols][pad][align]

__device__ __forceinline__ float4 conv9_3(float4 a, float4 b, float4 c,
                                          const float* w) {
    float X[12] = {a.x, a.y, a.z, a.w, b.x, b.y, b.z, b.w, c.x, c.y, c.z, c.w};
    float4 o = {0.f, 0.f, 0.f, 0.f};
#pragma unroll
    for (int j = 0; j < 9; ++j) {
        o.x = fmaf(w[j], X[j + 0], o.x);
        o.y = fmaf(w[j], X[j + 1], o.y);
        o.z = fmaf(w[j], X[j + 2], o.z);
        o.w = fmaf(w[j], X[j + 3], o.w);
    }
    return o;
}

__device__ __forceinline__ float4 sq4(float4 a) {
    return float4{a.x * a.x, a.y * a.y, a.z * a.z, a.w * a.w};
}

__global__ __launch_bounds__(128) void lcn_kernel(const float* __restrict__ x,
                                                  float* __restrict__ out,
                                                  W9 wts) {
    __shared__ float4 dring[DRING * DPITCH];

    const int tid = threadIdx.x;
    // Bijective XCD swizzle: 1024 blocks = 8 XCDs x 128. All 16 strips of an
    // image land on one XCD (and are co-resident) -> vertical-halo rows are
    // L2-shared instead of re-fetched from HBM.
    const int p = blockIdx.x;              // 0..1023
    const int lid = (p & 7) * 128 + (p >> 3);
    const int strip = lid & 15;            // 0..15
    const int img = lid >> 4;              // 0..63
    const int R0 = strip * SROWS;

    const float* xb = x + (size_t)img * HW * HW;
    float* ob = out + (size_t)img * HW * HW;

    float w[9];
#pragma unroll
    for (int i = 0; i < 9; ++i) w[i] = wts.w[i];

    // zero the pad columns (f4 index 0 and 129) of every ring slot, once.
    if (tid < DRING * 2) {
        dring[(tid >> 1) * DPITCH + (tid & 1) * (NF4 + 1)] =
            float4{0.f, 0.f, 0.f, 0.f};
    }

    const int c = tid;                      // f4 column owned by this lane
    const bool pl = (c > 0), pr = (c < NF4 - 1);
    const float4 zero4 = {0.f, 0.f, 0.f, 0.f};

    float4 hx[12];   // h-conv(x) ring, row r at slot (r-R0+8)%12 == s%12
    float4 h2r[12];  // h-conv(d^2) ring, row t at slot (t-R0+4)%12

#pragma unroll 1
    for (int rb = 0; rb < NSTEP; rb += 12) {
#pragma unroll
        for (int pp = 0; pp < 12; ++pp) {
            const int s = rb + pp;          // step index, ring phase = pp
            const int r = R0 - 8 + s;       // row being loaded this step

            // ---- stage A: hx(r) = h-conv of x row r (0 outside image) ----
            float4 hv = zero4;
            if (r >= 0 && r < HW) {
                const float4* row =
                    reinterpret_cast<const float4*>(xb + (size_t)r * HW);
                float4 xl = pl ? row[c - 1] : zero4;
                float4 xc = row[c];
                float4 xr = pr ? row[c + 1] : zero4;
                hv = conv9_3(xl, xc, xr, w);
            }
            hx[pp] = hv;

            // ---- stage B: mean(rd), d(rd) = x - mean; write LDS ring ----
            float4 d4 = zero4;
            if (s >= 8) {
                const int rd = r - 4;       // row r-4: all hx taps ready
                if (rd >= 0 && rd < HW) {
                    float4 mean = zero4;
#pragma unroll
                    for (int j = 0; j < 9; ++j) {
                        // hx(rd-4+j) was written at step s-8+j -> slot (pp+4+j)%12
                        const float4 h = hx[(pp + 4 + j) % 12];
                        mean.x = fmaf(w[j], h.x, mean.x);
                        mean.y = fmaf(w[j], h.y, mean.y);
                        mean.z = fmaf(w[j], h.z, mean.z);
                        mean.w = fmaf(w[j], h.w, mean.w);
                    }
                    float4 xc = reinterpret_cast<const float4*>(
                        xb + (size_t)rd * HW)[c];
                    d4.x = xc.x - mean.x; d4.y = xc.y - mean.y;
                    d4.z = xc.z - mean.z; d4.w = xc.w - mean.w;
                }
                // slot s%6 == pp%6 (rb % 6 == 0). Out-read happens at s+4
                // (slot distance 4 < 6), neighbor-read this step: safe.
                dring[(pp % 6) * DPITCH + 1 + c] = d4;
            }
            __syncthreads();

            // ---- stage C: h2(rd) = h-conv(d(rd)^2) from LDS ring ----
            if (s >= 8) {
                const float4* dr = &dring[(pp % 6) * DPITCH];
                float4 dl = dr[c];          // col c-1 (pads give zero at edge)
                float4 drt = dr[c + 2];     // col c+1
                // h2 row rd stored at slot (rd-R0+4)%12 = (s-8)%12 = (pp+4)%12
                h2r[(pp + 4) % 12] = conv9_3(sq4(dl), sq4(d4), sq4(drt), w);
            }

            // ---- stage D: n2(ro), normalize, store ----
            if (s >= 16) {
                const int ro = r - 8;       // output row, in [R0, R0+SROWS)
                float4 n2 = zero4;
#pragma unroll
                for (int j = 0; j < 9; ++j) {
                    // h2(ro-4+j) at slot (ro-4+j-R0+4)%12 = (s-16+j)%12 = (pp+8+j)%12
                    const float4 h = h2r[(pp + 8 + j) % 12];
                    n2.x = fmaf(w[j], h.x, n2.x);
                    n2.y = fmaf(w[j], h.y, n2.y);
                    n2.z = fmaf(w[j], h.z, n2.z);
                    n2.w = fmaf(w[j], h.w, n2.w);
                }
                // d(ro) was written at step s-4 -> slot (s-4)%6 = (pp+2)%6
                float4 dv = dring[((pp + 2) % 6) * DPITCH + 1 + c];
                // keep <=> sqrt(n2) > 0.5 <=> n2 > 0.25
                float4 o;
                o.x = (n2.x > 0.25f) ? dv.x * rsqrtf(n2.x) : dv.x;
                o.y = (n2.y > 0.25f) ? dv.y * rsqrtf(n2.y) : dv.y;
                o.z = (n2.z > 0.25f) ? dv.z * rsqrtf(n2.z) : dv.z;
                o.w = (n2.w > 0.25f) ? dv.w * rsqrtf(n2.w) : dv.w;
                reinterpret_cast<float4*>(ob + (size_t)ro * HW)[c] = o;
            }
        }
    }
}

static W9 make_w() {
    // reference: sigmah = 9/6, exponent divides by 2*sigmah = 3.0;
    // taps centered at 4.5 (asymmetric), separable: w1 = g1 / sum(g1).
    double g[9], sum = 0.0;
    for (int i = 0; i < 9; ++i) {
        double off = (double)i - 4.5;
        g[i] = exp(-(off * off) / 3.0);
        sum += g[i];
    }
    W9 r;
    for (int i = 0; i < 9; ++i) r.w[i] = (float)(g[i] / sum);
    return r;
}

extern "C" void kernel_launch(void* const* d_in, const int* in_sizes, int n_in,
                              void* d_out, int out_size, void* d_ws, size_t ws_size,
                              hipStream_t stream) {
    const float* x = (const float*)d_in[0];
    float* out = (float*)d_out;
    W9 w = make_w();
    // 64 images x 16 strips of 32 rows = 1024 blocks, 128 threads each.
    lcn_kernel<<<dim3(1024), dim3(128), 0, stream>>>(x, out, w);
}